// Round 10
// baseline (233.700 us; speedup 1.0000x reference)
//
#include <hip/hip_runtime.h>
#include <cstdint>

#define DIM   768
#define HEADS 12
#define HDIM  64
#define BATCH 4
#define SEQ   2048
#define MROWS (BATCH*SEQ)   // 8192

typedef __bf16 bf16;
typedef __bf16 bf16x4_t __attribute__((ext_vector_type(4)));
typedef __bf16 bf16x8_t __attribute__((ext_vector_type(8)));
typedef float  f32x4_t  __attribute__((ext_vector_type(4)));
typedef float  f32x16_t __attribute__((ext_vector_type(16)));

// ---------------- fused fp32 -> bf16 casts (x + 4 weights, one launch) ----------------
__global__ void cast_all_kernel(const float* __restrict__ x,
                                const float* __restrict__ w0, const float* __restrict__ w1,
                                const float* __restrict__ w2, const float* __restrict__ w3,
                                bf16* __restrict__ xb,
                                bf16* __restrict__ d0, bf16* __restrict__ d1,
                                bf16* __restrict__ d2, bf16* __restrict__ d3,
                                int nx4, int nw4) {
    int y = blockIdx.y;
    const float* src = (y == 0) ? x : (y == 1) ? w0 : (y == 2) ? w1 : (y == 3) ? w2 : w3;
    bf16* dst        = (y == 0) ? xb : (y == 1) ? d0 : (y == 2) ? d1 : (y == 3) ? d2 : d3;
    int n4           = (y == 0) ? nx4 : nw4;
    int i = blockIdx.x * blockDim.x + threadIdx.x;
    if (i >= n4) return;
    const float4 v = reinterpret_cast<const float4*>(src)[i];
    bf16x4_t o;
    o[0] = (bf16)v.x; o[1] = (bf16)v.y; o[2] = (bf16)v.z; o[3] = (bf16)v.w;
    reinterpret_cast<bf16x4_t*>(dst)[i] = o;
}

// async global->LDS, 16B per lane. LDS dest is wave-uniform base + lane*16.
__device__ __forceinline__ void gload_lds16(const bf16* g, bf16* l) {
    __builtin_amdgcn_global_load_lds((const __attribute__((address_space(1))) void*)g,
                                     (__attribute__((address_space(3))) void*)l, 16, 0, 0);
}

// ---------------- merged projection GEMM v3: BK=32 double-buffered ----------------
// All slices: A = W{q,k,v} (M=dfull), B = X (N=sample) -> C[dfull][sample].
// Swizzle: 16B chunk ch (0..3) stored at ch ^ ((row>>1)&3) -> 2-way (free) b128 reads.
// z=0 -> Q (pre-scaled log2(e)/8) packed bf16x4; z=1 -> K packed; z=2 -> Vt row-major.
__global__ __launch_bounds__(256, 4) void qkvv_gemm(
        const bf16* __restrict__ X,
        const bf16* __restrict__ Wq, const bf16* __restrict__ Wk, const bf16* __restrict__ Wv,
        bf16* __restrict__ Q, bf16* __restrict__ Kd, bf16* __restrict__ Vt)
{
    __shared__ __align__(16) bf16 As[2][128*32];
    __shared__ __align__(16) bf16 Bs[2][128*32];
    const int tid  = threadIdx.x;
    const int z    = blockIdx.z;
    const bf16* Ap = (z == 0) ? Wq : (z == 1 ? Wk : Wv);
    const int m0   = blockIdx.x * 128;   // dfull
    const int n0   = blockIdx.y * 128;   // sample
    const int lane = tid & 63;
    const int w    = tid >> 6;
    const int wm   = (w & 1) * 64, wn = (w >> 1) * 64;
    const int lr   = lane & 15, quad = lane >> 4;

    // staging coords: slot s -> row = s>>2, ch = s&3, src chunk gch = ch ^ ((row>>1)&3)
    const int r1 = tid >> 2,        c1 = tid & 3,  g1 = c1 ^ ((r1 >> 1) & 3);
    const int r2 = 64 + (tid >> 2), c2 = tid & 3,  g2 = c2 ^ ((r2 >> 1) & 3);
    const bf16* a1 = Ap + (size_t)(m0 + r1) * DIM + g1 * 8;
    const bf16* a2 = Ap + (size_t)(m0 + r2) * DIM + g2 * 8;
    const bf16* b1 = X  + (size_t)(n0 + r1) * DIM + g1 * 8;
    const bf16* b2 = X  + (size_t)(n0 + r2) * DIM + g2 * 8;
    const int l1 = r1 * 32 + c1 * 8, l2 = r2 * 32 + c2 * 8;

    auto stage = [&](int kk, int buf) {
        gload_lds16(a1 + kk, &As[buf][l1]);
        gload_lds16(a2 + kk, &As[buf][l2]);
        gload_lds16(b1 + kk, &Bs[buf][l1]);
        gload_lds16(b2 + kk, &Bs[buf][l2]);
    };

    f32x4_t acc[4][4] = {};
    stage(0, 0);
    __syncthreads();

    const int NIT = DIM / 32;   // 24
    for (int it = 0; it < NIT; ++it) {
        const int buf = it & 1;
        if (it + 1 < NIT) stage((it + 1) * 32, buf ^ 1);

        bf16x8_t af[4], bfr[4];
        #pragma unroll
        for (int i = 0; i < 4; ++i) {
            int row = wm + i * 16 + lr;
            int ch = quad ^ ((row >> 1) & 3);
            af[i] = *reinterpret_cast<const bf16x8_t*>(&As[buf][row * 32 + ch * 8]);
        }
        #pragma unroll
        for (int j = 0; j < 4; ++j) {
            int row = wn + j * 16 + lr;
            int ch = quad ^ ((row >> 1) & 3);
            bfr[j] = *reinterpret_cast<const bf16x8_t*>(&Bs[buf][row * 32 + ch * 8]);
        }
        #pragma unroll
        for (int i = 0; i < 4; ++i)
            #pragma unroll
            for (int j = 0; j < 4; ++j)
                acc[i][j] = __builtin_amdgcn_mfma_f32_16x16x32_bf16(af[i], bfr[j], acc[i][j], 0, 0, 0);
        __syncthreads();
    }

    if (z == 2) {
        #pragma unroll
        for (int i = 0; i < 4; ++i) {
            int mbase = m0 + wm + i * 16 + quad * 4;
            #pragma unroll
            for (int j = 0; j < 4; ++j) {
                int n = n0 + wn + j * 16 + lr;
                #pragma unroll
                for (int r = 0; r < 4; ++r)
                    Vt[(size_t)(mbase + r) * MROWS + n] = (bf16)acc[i][j][r];
            }
        }
    } else {
        const float sc = (z == 0) ? 0.18033688011112042f : 1.0f;   // log2(e)/8 into Q
        bf16* dst = (z == 0) ? Q : Kd;
        #pragma unroll
        for (int i = 0; i < 4; ++i) {
            int mb = m0 + wm + i * 16 + quad * 4;
            int h  = mb >> 6, d0 = mb & 63;
            #pragma unroll
            for (int j = 0; j < 4; ++j) {
                int sample = n0 + wn + j * 16 + lr;
                int b = sample >> 11, srow = sample & 2047;
                bf16x4_t o;
                #pragma unroll
                for (int r = 0; r < 4; ++r)
                    o[r] = (bf16)(acc[i][j][r] * sc);
                *reinterpret_cast<bf16x4_t*>(
                    &dst[(((size_t)b * HEADS + h) * SEQ + srow) * HDIM + d0]) = o;
            }
        }
    }
}

// ---------------- output projection GEMM: 64x128, BK=32 double-buffered ----------------
__global__ __launch_bounds__(256, 4) void out_gemm(
        const bf16* __restrict__ A,       // [8192,768]
        const bf16* __restrict__ W,       // [768,768]
        const float* __restrict__ bias,
        float* __restrict__ out)          // [8192,768] f32
{
    __shared__ __align__(16) bf16 As[2][64*32];
    __shared__ __align__(16) bf16 Bs[2][128*32];
    const int tid  = threadIdx.x;
    const int n0   = blockIdx.x * 128;
    const int m0   = blockIdx.y * 64;
    const int lane = tid & 63;
    const int w    = tid >> 6;
    const int wm   = (w & 1) * 32, wn = (w >> 1) * 64;
    const int lr   = lane & 15, quad = lane >> 4;

    const int r1 = tid >> 2,        c1 = tid & 3,  g1 = c1 ^ ((r1 >> 1) & 3);
    const int r2 = 64 + (tid >> 2), c2 = tid & 3,  g2 = c2 ^ ((r2 >> 1) & 3);
    const bf16* a1 = A + (size_t)(m0 + r1) * DIM + g1 * 8;           // As: 64 rows (r1 only)
    const bf16* b1 = W + (size_t)(n0 + r1) * DIM + g1 * 8;
    const bf16* b2 = W + (size_t)(n0 + r2) * DIM + g2 * 8;
    const int l1 = r1 * 32 + c1 * 8, l2 = r2 * 32 + c2 * 8;

    auto stage = [&](int kk, int buf) {
        gload_lds16(a1 + kk, &As[buf][l1]);
        gload_lds16(b1 + kk, &Bs[buf][l1]);
        gload_lds16(b2 + kk, &Bs[buf][l2]);
    };

    f32x4_t acc[2][4] = {};
    stage(0, 0);
    __syncthreads();

    const int NIT = DIM / 32;
    for (int it = 0; it < NIT; ++it) {
        const int buf = it & 1;
        if (it + 1 < NIT) stage((it + 1) * 32, buf ^ 1);

        bf16x8_t af[2], bfr[4];
        #pragma unroll
        for (int i = 0; i < 2; ++i) {
            int row = wm + i * 16 + lr;
            int ch = quad ^ ((row >> 1) & 3);
            af[i] = *reinterpret_cast<const bf16x8_t*>(&As[buf][row * 32 + ch * 8]);
        }
        #pragma unroll
        for (int j = 0; j < 4; ++j) {
            int row = wn + j * 16 + lr;
            int ch = quad ^ ((row >> 1) & 3);
            bfr[j] = *reinterpret_cast<const bf16x8_t*>(&Bs[buf][row * 32 + ch * 8]);
        }
        #pragma unroll
        for (int i = 0; i < 2; ++i)
            #pragma unroll
            for (int j = 0; j < 4; ++j)
                acc[i][j] = __builtin_amdgcn_mfma_f32_16x16x32_bf16(af[i], bfr[j], acc[i][j], 0, 0, 0);
        __syncthreads();
    }

    #pragma unroll
    for (int i = 0; i < 2; ++i) {
        int mbase = m0 + wm + i * 16 + quad * 4;
        #pragma unroll
        for (int j = 0; j < 4; ++j) {
            int n = n0 + wn + j * 16 + lr;
            float bv = bias[n];
            #pragma unroll
            for (int r = 0; r < 4; ++r) {
                int m = mbase + r;
                out[(size_t)m * DIM + n] = acc[i][j][r] + bv;
            }
        }
    }
}

// ---------------- flash attention v6 (round-8, unchanged) ----------------
__global__ __launch_bounds__(256, 3) void attn_kernel(
        const bf16* __restrict__ Q, const bf16* __restrict__ Kd,
        const bf16* __restrict__ Vt, bf16* __restrict__ Ab)
{
    __shared__ __align__(16) bf16 KV[2][2][64*64];   // [buf][K|V][row*64] swizzled

    const int tid  = threadIdx.x;
    const int bh   = blockIdx.y;
    const int b    = bh / HEADS, h = bh % HEADS;
    const int q0   = blockIdx.x * 128;
    const int lane = tid & 63, w = tid >> 6;
    const int l31  = lane & 31, hw = lane >> 5;
    const int wq   = w * 32;

    const size_t qkbase = (size_t)bh * SEQ * HDIM;
    const size_t vbase  = (size_t)h * HDIM * MROWS + (size_t)b * SEQ;

    const int src_row = tid >> 3, src_ch = tid & 7;
    const int src_gch = src_ch ^ (src_row & 7);
    const int src_row2 = (tid + 256) >> 3, src_ch2 = tid & 7;
    const int src_gch2 = src_ch2 ^ (src_row2 & 7);

    {
        bf16* Qst = &KV[1][0][0];
        #pragma unroll
        for (int i = 0; i < 4; ++i) {
            int c = tid + i * 256;
            int row = c >> 3, ch = c & 7;
            int gch = ch ^ (row & 7);
            gload_lds16(Q + qkbase + (size_t)(q0 + row) * HDIM + gch * 8, &Qst[row * 64 + ch * 8]);
        }
    }

    const bf16* kp1 = Kd + qkbase + (size_t)src_row  * HDIM + src_gch  * 8;
    const bf16* kp2 = Kd + qkbase + (size_t)src_row2 * HDIM + src_gch2 * 8;
    const bf16* vp1 = Vt + vbase  + (size_t)src_row  * MROWS + src_gch  * 8;
    const bf16* vp2 = Vt + vbase  + (size_t)src_row2 * MROWS + src_gch2 * 8;
    bf16* kl1 = &KV[0][0][src_row  * 64 + src_ch  * 8];
    bf16* kl2 = &KV[0][0][src_row2 * 64 + src_ch2 * 8];
    bf16* vl1 = &KV[0][1][src_row  * 64 + src_ch  * 8];
    bf16* vl2 = &KV[0][1][src_row2 * 64 + src_ch2 * 8];
    const ptrdiff_t kstep = 64 * HDIM, vstep = 64;
    const ptrdiff_t lstep = 2 * 64 * 64;

    gload_lds16(kp1, kl1); gload_lds16(kp2, kl2);
    gload_lds16(vp1, vl1); gload_lds16(vp2, vl2);
    __syncthreads();

    bf16x8_t qf[4];
    {
        const bf16* Qst = &KV[1][0][0];
        int row = wq + l31;
        #pragma unroll
        for (int g = 0; g < 4; ++g) {
            int ch = (2 * g + hw) ^ (row & 7);
            qf[g] = *reinterpret_cast<const bf16x8_t*>(&Qst[row * 64 + ch * 8]);
        }
    }
    __syncthreads();

    f32x16_t oacc[2] = {};
    f32x16_t rsacc  = {};
    bf16x8_t ones8;
    #pragma unroll
    for (int i = 0; i < 8; ++i) ones8[i] = (bf16)1.0f;

    for (int it = 0; it < SEQ / 64; ++it) {
        const int buf = it & 1;
        if (it + 1 < SEQ / 64) {
            const ptrdiff_t g = (ptrdiff_t)(it + 1);
            const ptrdiff_t l = (buf ^ 1) ? lstep : 0;
            gload_lds16(kp1 + g * kstep, kl1 + l); gload_lds16(kp2 + g * kstep, kl2 + l);
            gload_lds16(vp1 + g * vstep, vl1 + l); gload_lds16(vp2 + g * vstep, vl2 + l);
        }

        const bf16* Ks = &KV[buf][0][0];
        const bf16* Vs = &KV[buf][1][0];

        f32x16_t sacc[2] = {};
        #pragma unroll
        for (int kc = 0; kc < 2; ++kc) {
            int row = kc * 32 + l31;
            #pragma unroll
            for (int g = 0; g < 4; ++g) {
                int ch = (2 * g + hw) ^ (row & 7);
                bf16x8_t af = *reinterpret_cast<const bf16x8_t*>(&Ks[row * 64 + ch * 8]);
                sacc[kc] = __builtin_amdgcn_mfma_f32_32x32x16_bf16(af, qf[g], sacc[kc], 0, 0, 0);
            }
        }

        bf16x8_t pk[4];
        #pragma unroll
        for (int kg = 0; kg < 4; ++kg) {
            #pragma unroll
            for (int j = 0; j < 8; ++j)
                pk[kg][j] = (bf16)__builtin_amdgcn_exp2f(sacc[kg >> 1][(kg & 1) * 8 + j]);
        }

        #pragma unroll
        for (int kg = 0; kg < 4; ++kg)
            rsacc = __builtin_amdgcn_mfma_f32_32x32x16_bf16(pk[kg], ones8, rsacc, 0, 0, 0);

        #pragma unroll
        for (int dc = 0; dc < 2; ++dc) {
            int row = dc * 32 + l31;
            #pragma unroll
            for (int kg = 0; kg < 4; ++kg) {
                int ch1 = (2 * kg)     ^ (row & 7);
                int ch2 = (2 * kg + 1) ^ (row & 7);
                bf16x4_t lo = *reinterpret_cast<const bf16x4_t*>(&Vs[row * 64 + ch1 * 8 + hw * 4]);
                bf16x4_t hi = *reinterpret_cast<const bf16x4_t*>(&Vs[row * 64 + ch2 * 8 + hw * 4]);
                bf16x8_t bb;
                bb[0]=lo[0]; bb[1]=lo[1]; bb[2]=lo[2]; bb[3]=lo[3];
                bb[4]=hi[0]; bb[5]=hi[1]; bb[6]=hi[2]; bb[7]=hi[3];
                oacc[dc] = __builtin_amdgcn_mfma_f32_32x32x16_bf16(pk[kg], bb, oacc[dc], 0, 0, 0);
            }
        }
        __syncthreads();
    }

    float inv[16];
    #pragma unroll
    for (int r = 0; r < 16; ++r)
        inv[r] = 1.0f / rsacc[r];
    #pragma unroll
    for (int dc = 0; dc < 2; ++dc) {
        int d = dc * 32 + l31;
        #pragma unroll
        for (int r = 0; r < 16; ++r) {
            int q = q0 + wq + (r & 3) + 8 * (r >> 2) + 4 * hw;
            Ab[((size_t)b * SEQ + q) * DIM + h * HDIM + d] = (bf16)(oacc[dc][r] * inv[r]);
        }
    }
}

extern "C" void kernel_launch(void* const* d_in, const int* in_sizes, int n_in,
                              void* d_out, int out_size, void* d_ws, size_t ws_size,
                              hipStream_t stream) {
    (void)in_sizes; (void)n_in; (void)out_size; (void)ws_size;
    const float* x  = (const float*)d_in[0];
    const float* Wq = (const float*)d_in[1];
    const float* Wk = (const float*)d_in[2];
    const float* Wv = (const float*)d_in[3];
    const float* Wp = (const float*)d_in[4];
    const float* bp = (const float*)d_in[5];
    float* out = (float*)d_out;

    char* ws = (char*)d_ws;
    size_t off = 0;
    auto alloc = [&](size_t bytes) {
        void* p = ws + off;
        off += (bytes + 255) & ~(size_t)255;
        return p;
    };
    const size_t big = (size_t)MROWS * DIM * sizeof(bf16);
    const size_t wsz = (size_t)DIM * DIM * sizeof(bf16);
    bf16* Xb  = (bf16*)alloc(big);
    bf16* Qb  = (bf16*)alloc(big);
    bf16* Kb  = (bf16*)alloc(big);
    bf16* Vtb = (bf16*)alloc(big);
    bf16* Wqb = (bf16*)alloc(wsz);
    bf16* Wkb = (bf16*)alloc(wsz);
    bf16* Wvb = (bf16*)alloc(wsz);
    bf16* Wpb = (bf16*)alloc(wsz);
    bf16* Ab  = Xb;   // Xb dead after projections

    const int nx4 = MROWS * DIM / 4;      // 1572864/4
    const int nw4 = DIM * DIM / 4;
    cast_all_kernel<<<dim3((nx4 + 255) / 256, 5), 256, 0, stream>>>(
        x, Wq, Wk, Wv, Wp, Xb, Wqb, Wkb, Wvb, Wpb, nx4, nw4);

    qkvv_gemm<<<dim3(DIM / 128, MROWS / 128, 3), 256, 0, stream>>>(
        Xb, Wqb, Wkb, Wvb, Qb, Kb, Vtb);

    attn_kernel<<<dim3(SEQ / 128, BATCH * HEADS), 256, 0, stream>>>(Qb, Kb, Vtb, Ab);

    out_gemm<<<dim3(DIM / 128, MROWS / 64), 256, 0, stream>>>(Ab, Wpb, bp, out);
}